// Round 8
// baseline (613.956 us; speedup 1.0000x reference)
//
#include <hip/hip_runtime.h>
#include <hip/hip_bf16.h>

// ---------------------------------------------------------------------------
// ConvTokenEmbedder: char-CNN -> 2x highway -> projection
// R8: GEMM LDS tiles stored in FRAGMENT ORDER: slot(seg*64+lane) holds
//     (row=(wave*2+(it>>1))*16+frow, chunk=(it&1)*4+q). Fragment reads become
//     ds_read_b128 at [wave-uniform imm offset + lane*16] -> conflict-free
//     AND zero per-read VALU (offset immediates), no swizzle math.
//     (R7's source-XOR swizzle fixed conflicts but moved cost to VALU:
//      VALUBusy 24->33, dur 129->151. This kills both.)
// Conv: classes 0/1 get GROUPS=4 (256-block grids; were half-idle at 128).
// ---------------------------------------------------------------------------

#define NTOK 4096
#define NF   2048
#define KDIM 2048
#define HID  4096
#define PDIM 512

typedef __attribute__((ext_vector_type(4))) float floatx4;
typedef __attribute__((ext_vector_type(8))) short shortx8;

__device__ inline void async_copy16(const void* g, void* l) {
  __builtin_amdgcn_global_load_lds(
      (const __attribute__((address_space(1))) void*)(uintptr_t)g,
      (__attribute__((address_space(3))) void*)(uint32_t)(uintptr_t)l,
      16, 0, 0);
}

// ---------------------------------------------------------------------------
__global__ __launch_bounds__(256) void cvt_kernel(
    const float* __restrict__ s, __hip_bfloat16* __restrict__ d, int n) {
  int i = blockIdx.x * 256 + threadIdx.x;
  if (i < n) d[i] = __float2bfloat16(s[i]);
}

// Highway weight cvt with nl/gate row interleave: dst row r = src row
// (r>>1) + (r&1)*2048. So cols 2j/2j+1 of p' are (nl_j, gate_j).
__global__ __launch_bounds__(256) void cvt_hw(
    const float* __restrict__ s, __hip_bfloat16* __restrict__ d) {
  int i = blockIdx.x * 256 + threadIdx.x;  // over 4096*2048
  int r = i >> 11, k = i & 2047;
  int sr = (r >> 1) + (r & 1) * 2048;
  d[i] = __float2bfloat16(s[(size_t)sr * 2048 + k]);
}

// ---------------------------------------------------------------------------
// Conv weight prep: Wb[ch][kp], kp = k*16+d, K padded to 128 (zeros k>=w).
// Plus bias pack [2048] and bf16 emb table [262*16].
// ---------------------------------------------------------------------------
__global__ __launch_bounds__(256) void conv_wprep(
    const float* __restrict__ w0, const float* __restrict__ w1,
    const float* __restrict__ w2, const float* __restrict__ w3,
    const float* __restrict__ w4, const float* __restrict__ w5,
    const float* __restrict__ w6,
    const float* __restrict__ b0, const float* __restrict__ b1,
    const float* __restrict__ b2, const float* __restrict__ b3,
    const float* __restrict__ b4, const float* __restrict__ b5,
    const float* __restrict__ b6, const float* __restrict__ emb,
    __hip_bfloat16* __restrict__ Wb, float* __restrict__ Bc,
    __hip_bfloat16* __restrict__ embb) {
  int idx = blockIdx.x * 256 + threadIdx.x;
  const int start[7] = {0, 32, 64, 128, 256, 512, 1024};
  const float* ws[7] = {w0, w1, w2, w3, w4, w5, w6};
  const float* bs[7] = {b0, b1, b2, b3, b4, b5, b6};
  if (idx < 262144) {
    int ch = idx >> 7, kp = idx & 127;
    int f = (ch >= 32) + (ch >= 64) + (ch >= 128) + (ch >= 256) +
            (ch >= 512) + (ch >= 1024);
    int w = f + 1, lc = ch - start[f];
    int d = kp & 15, k = kp >> 4;
    float v = (k < w) ? ws[f][((size_t)lc * 16 + d) * w + k] : 0.f;
    Wb[idx] = __float2bfloat16(v);
  } else if (idx < 262144 + 2048) {
    int ch = idx - 262144;
    int f = (ch >= 32) + (ch >= 64) + (ch >= 128) + (ch >= 256) +
            (ch >= 512) + (ch >= 1024);
    Bc[ch] = bs[f][ch - start[f]];
  } else if (idx < 262144 + 2048 + 4192) {
    int e = idx - 262144 - 2048;
    embb[e] = __float2bfloat16(emb[e]);
  }
}

// ---------------------------------------------------------------------------
// Conv kernel. Block: 64 channels x GROUPS*4 tokens; groups of 4 tokens
// (one per wave). A = X window tile (rows=t, stride 24 -> 2-way only),
// B = W register-resident. Epilogue: register max over t, shfl 16/32,
// cndmask select, one coalesced 128B store per wave per group.
// ---------------------------------------------------------------------------
template <int NKT, int NT, int ROWS, int GROUPS>
__global__ __launch_bounds__(256) void conv_k(
    const int* __restrict__ chars, const __hip_bfloat16* __restrict__ embb,
    const __hip_bfloat16* __restrict__ Wb, const float* __restrict__ bias,
    __hip_bfloat16* __restrict__ h, int chbase) {
  __shared__ __align__(16) __hip_bfloat16 Xs[2 * 4 * ROWS * 24];
  int tid = threadIdx.x, wave = tid >> 6, lane = tid & 63;
  int frow = lane & 15, q = lane >> 4;
  int chb = chbase + blockIdx.y * 64;
  int tokbase = blockIdx.x * (GROUPS * 4);

  // W fragments (B operand): B[n=frow=ch][k=q*8+jj], register-resident.
  shortx8 wreg[NKT][4];
#pragma unroll
  for (int kt = 0; kt < NKT; ++kt)
#pragma unroll
    for (int j = 0; j < 4; ++j)
      wreg[kt][j] = *(const shortx8*)(
          Wb + (size_t)(chb + j * 16 + frow) * 128 + kt * 32 + q * 8);

  float blane = bias[chb + lane];
  int Tvj[4];
#pragma unroll
  for (int j = 0; j < 4; ++j) {
    int ch = chb + j * 16 + frow;
    int w = 1 + (ch >= 32) + (ch >= 64) + (ch >= 128) + (ch >= 256) +
            (ch >= 512) + (ch >= 1024);
    Tvj[j] = 51 - w;
  }

  auto stage = [&](int g, int buf) {
    constexpr int NST = 4 * ROWS;
#pragma unroll
    for (int rep = 0; rep < (NST + 255) / 256; ++rep) {
      int rr = tid + rep * 256;
      if (rr < NST) {
        int tk = rr / ROWS, r = rr - tk * ROWS;
        __hip_bfloat16* dst = Xs + ((size_t)(buf * 4 + tk) * ROWS + r) * 24;
        if (r < 50) {
          int c = chars[(size_t)(tokbase + g * 4 + tk) * 50 + r];
          const shortx8* e = (const shortx8*)(embb + c * 16);
          *(shortx8*)(dst) = e[0];
          *(shortx8*)(dst + 8) = e[1];
        } else if (g <= 1) {
          shortx8 z = {0, 0, 0, 0, 0, 0, 0, 0};
          *(shortx8*)(dst) = z;
          *(shortx8*)(dst + 8) = z;
        }
      }
    }
  };

  stage(0, 0);
  __syncthreads();

  const floatx4 zero = {0.f, 0.f, 0.f, 0.f};
#pragma unroll 1
  for (int g = 0; g < GROUPS; ++g) {
    if (g < GROUPS - 1) stage(g + 1, (g + 1) & 1);

    const __hip_bfloat16* Xw = Xs + (size_t)((g & 1) * 4 + wave) * ROWS * 24;
    floatx4 acc[NT][4];

#pragma unroll
    for (int kt = 0; kt < NKT; ++kt) {
      int kk = kt * 2 + (q >> 1);
      int d0 = (q & 1) * 8;
      shortx8 xf[NT];
#pragma unroll
      for (int i = 0; i < NT; ++i)
        xf[i] = *(const shortx8*)(Xw + (i * 16 + frow + kk) * 24 + d0);
#pragma unroll
      for (int i = 0; i < NT; ++i)
#pragma unroll
        for (int j = 0; j < 4; ++j) {
          if (kt == 0)
            acc[i][j] = __builtin_amdgcn_mfma_f32_16x16x32_bf16(
                xf[i], wreg[0][j], zero, 0, 0, 0);
          else
            acc[i][j] = __builtin_amdgcn_mfma_f32_16x16x32_bf16(
                xf[i], wreg[kt][j], acc[i][j], 0, 0, 0);
        }
    }

    float vj[4];
#pragma unroll
    for (int j = 0; j < 4; ++j) {
      float v = -1e30f;
#pragma unroll
      for (int i = 0; i < NT; ++i) {
#pragma unroll
        for (int r = 0; r < 4; ++r) {
          if (i < 2) {  // t <= 31 < Tv_min=44: always valid
            v = fmaxf(v, acc[i][j][r]);
          } else {
            int t = i * 16 + q * 4 + r;
            if (t < Tvj[j]) v = fmaxf(v, acc[i][j][r]);
          }
        }
      }
      v = fmaxf(v, __shfl_xor(v, 16));
      v = fmaxf(v, __shfl_xor(v, 32));
      vj[j] = v;
    }
    float r0 = (q & 2) ? vj[2] : vj[0];
    float r1 = (q & 2) ? vj[3] : vj[1];
    float rv = (q & 1) ? r1 : r0;
    int tok = tokbase + g * 4 + wave;
    h[(size_t)tok * NF + chb + lane] =
        __float2bfloat16(fmaxf(rv + blane, 0.f));
    __syncthreads();
  }
}

// ---------------------------------------------------------------------------
// Highway-fused GEMM, BK=64, 128x128 tile, fragment-order LDS.
// Staging: seg = wave*4+it stages 1024B; lane's source = row
// (wave*2+(it>>1))*16+frow, chunk (it&1)*4+q. Then frag read (i,s) is at
// byte offset (wr*4+i)*2048 + s*1024 + lane*16: wave-uniform immediate +
// lane*16 -> conflict-free, zero address VALU.
// Epilogue: pairs even/odd cols via shfl_xor(1), g=sigmoid(gate+b),
// h' = g*h + (1-g)*relu(nl+b), writes Hdst.
// ---------------------------------------------------------------------------
__global__ __launch_bounds__(256) void gemm_hw(
    const __hip_bfloat16* __restrict__ A, const __hip_bfloat16* __restrict__ B,
    const float* __restrict__ hwb, __hip_bfloat16* __restrict__ Hdst) {
  const int K = KDIM;
  __shared__ __align__(16) __hip_bfloat16 As[128 * 64];
  __shared__ __align__(16) __hip_bfloat16 Bs[128 * 64];
  int tid = threadIdx.x;
  int wave = tid >> 6, lane = tid & 63;
  int wr = wave >> 1, wc = wave & 1;
  int bn = blockIdx.y, bm = blockIdx.x;

  int frow = lane & 15;
  int q    = lane >> 4;

  floatx4 acc[4][4];
  floatx4 zero = {0.f, 0.f, 0.f, 0.f};
#pragma unroll
  for (int i = 0; i < 4; ++i)
#pragma unroll
    for (int j = 0; j < 4; ++j) acc[i][j] = zero;

  const __hip_bfloat16* Ab = A + (size_t)bn * 128 * K;
  const __hip_bfloat16* Bb = B + (size_t)bm * 128 * K;
  const char* Ard = (const char*)As + lane * 16;
  const char* Brd = (const char*)Bs + lane * 16;

  for (int kb = 0; kb < K; kb += 64) {
    __syncthreads();
#pragma unroll
    for (int it = 0; it < 4; ++it) {
      int row = (wave * 2 + (it >> 1)) * 16 + frow;
      int ck  = (it & 1) * 4 + q;
      size_t src = (size_t)row * K + kb + ck * 8;
      async_copy16(Ab + src, (char*)As + (wave * 4 + it) * 1024);
      async_copy16(Bb + src, (char*)Bs + (wave * 4 + it) * 1024);
    }
    __syncthreads();

#pragma unroll
    for (int s = 0; s < 2; ++s) {
      shortx8 af[4], bf[4];
#pragma unroll
      for (int i = 0; i < 4; ++i)
        af[i] = *(const shortx8*)(Ard + (wr * 4 + i) * 2048 + s * 1024);
#pragma unroll
      for (int j = 0; j < 4; ++j)
        bf[j] = *(const shortx8*)(Brd + (wc * 4 + j) * 2048 + s * 1024);
#pragma unroll
      for (int i = 0; i < 4; ++i)
#pragma unroll
        for (int j = 0; j < 4; ++j)
          acc[i][j] = __builtin_amdgcn_mfma_f32_16x16x32_bf16(
              af[i], bf[j], acc[i][j], 0, 0, 0);
    }
  }

  int crow0 = bn * 128 + wr * 64 + q * 4;
  int ccol0 = bm * 128 + wc * 64 + frow;
#pragma unroll
  for (int i = 0; i < 4; ++i)
#pragma unroll
    for (int j = 0; j < 4; ++j) {
      int gcol = ccol0 + j * 16;
      float bb = (gcol & 1) ? hwb[2048 + (gcol >> 1)] : hwb[gcol >> 1];
#pragma unroll
      for (int r = 0; r < 4; ++r) {
        int row = crow0 + i * 16 + r;
        float v = acc[i][j][r] + bb;
        float partner = __shfl_xor(v, 1);
        if (!(lane & 1)) {  // even lane holds nl, partner is gate pre-act
          float gte = 1.f / (1.f + expf(-partner));
          int ch = gcol >> 1;
          float hold = __bfloat162float(A[(size_t)row * 2048 + ch]);
          float hnew = gte * hold + (1.f - gte) * fmaxf(v, 0.f);
          Hdst[(size_t)row * 2048 + ch] = __float2bfloat16(hnew);
        }
      }
    }
}

// ---------------------------------------------------------------------------
// Projection GEMM: 32x128 tile (grid 4x128 = 512 blocks), BK=64,
// fragment-order LDS (As: 4 segs; Bs: 16 segs). C fp32 + bias.
// ---------------------------------------------------------------------------
__global__ __launch_bounds__(256) void gemm_proj(
    const __hip_bfloat16* __restrict__ A, const __hip_bfloat16* __restrict__ B,
    float* __restrict__ C, const float* __restrict__ bias) {
  const int K = KDIM;
  __shared__ __align__(16) __hip_bfloat16 As[32 * 64];
  __shared__ __align__(16) __hip_bfloat16 Bs[128 * 64];
  int tid = threadIdx.x;
  int wave = tid >> 6, lane = tid & 63;
  int wr = wave >> 1, wc = wave & 1;
  int bn = blockIdx.y, bm = blockIdx.x;

  int frow = lane & 15, q = lane >> 4;

  floatx4 acc[4];
  floatx4 zero = {0.f, 0.f, 0.f, 0.f};
#pragma unroll
  for (int j = 0; j < 4; ++j) acc[j] = zero;

  const __hip_bfloat16* Ab = A + (size_t)bn * 32 * K;
  const __hip_bfloat16* Bb = B + (size_t)bm * 128 * K;
  const char* Ard = (const char*)As + lane * 16;
  const char* Brd = (const char*)Bs + lane * 16;

  for (int kb = 0; kb < K; kb += 64) {
    __syncthreads();
    {
      // As: seg = wave; row = (wave>>1)*16+frow, chunk = (wave&1)*4+q
      int row = (wave >> 1) * 16 + frow;
      int ck  = (wave & 1) * 4 + q;
      async_copy16(Ab + (size_t)row * K + kb + ck * 8,
                   (char*)As + wave * 1024);
    }
#pragma unroll
    for (int it = 0; it < 4; ++it) {
      int row = (wave * 2 + (it >> 1)) * 16 + frow;
      int ck  = (it & 1) * 4 + q;
      async_copy16(Bb + (size_t)row * K + kb + ck * 8,
                   (char*)Bs + (wave * 4 + it) * 1024);
    }
    __syncthreads();

#pragma unroll
    for (int s = 0; s < 2; ++s) {
      shortx8 af, bf[4];
      af = *(const shortx8*)(Ard + wr * 2048 + s * 1024);
#pragma unroll
      for (int j = 0; j < 4; ++j)
        bf[j] = *(const shortx8*)(Brd + (wc * 4 + j) * 2048 + s * 1024);
#pragma unroll
      for (int j = 0; j < 4; ++j)
        acc[j] = __builtin_amdgcn_mfma_f32_16x16x32_bf16(af, bf[j], acc[j],
                                                          0, 0, 0);
    }
  }

  int crow0 = bn * 32 + wr * 16 + q * 4;
  int ccol0 = bm * 128 + wc * 64 + frow;
#pragma unroll
  for (int j = 0; j < 4; ++j) {
    int c = ccol0 + j * 16;
#pragma unroll
    for (int r = 0; r < 4; ++r) {
      int row = crow0 + r;
      C[(size_t)row * PDIM + c] = acc[j][r] + bias[c];
    }
  }
}

// ---------------------------------------------------------------------------
extern "C" void kernel_launch(void* const* d_in, const int* in_sizes, int n_in,
                              void* d_out, int out_size, void* d_ws, size_t ws_size,
                              hipStream_t stream) {
  const int*   chars  = (const int*)d_in[1];
  const float* emb    = (const float*)d_in[2];
  const float* cw[7];
  const float* cb[7];
  for (int i = 0; i < 7; ++i) {
    cw[i] = (const float*)d_in[3 + 2 * i];
    cb[i] = (const float*)d_in[4 + 2 * i];
  }
  const float* hw_w0  = (const float*)d_in[17];
  const float* hw_b0  = (const float*)d_in[18];
  const float* hw_w1  = (const float*)d_in[19];
  const float* hw_b1  = (const float*)d_in[20];
  const float* proj_w = (const float*)d_in[21];
  const float* proj_b = (const float*)d_in[22];
  float* out = (float*)d_out;

  // Workspace (82 MiB):
  //   [0,16)   h   bf16 4096x2048      [16,32) h2  bf16 4096x2048
  //   [32,48)  convWb 512KB + convBc 8KB + embb 8.4KB
  //   [48,64)  w0b  [64,80) w1b  [80,82) pwb
  char* ws = (char*)d_ws;
  __hip_bfloat16* h      = (__hip_bfloat16*)(ws);
  __hip_bfloat16* h2     = (__hip_bfloat16*)(ws + (16ull << 20));
  __hip_bfloat16* convWb = (__hip_bfloat16*)(ws + (32ull << 20));
  float*          convBc = (float*)(ws + (32ull << 20) + 524288);
  __hip_bfloat16* embb   = (__hip_bfloat16*)(ws + (32ull << 20) + 524288 + 8192);
  __hip_bfloat16* w0b    = (__hip_bfloat16*)(ws + (48ull << 20));
  __hip_bfloat16* w1b    = (__hip_bfloat16*)(ws + (64ull << 20));
  __hip_bfloat16* pwb    = (__hip_bfloat16*)(ws + (80ull << 20));

  cvt_hw<<<(HID * KDIM) / 256, 256, 0, stream>>>(hw_w0, w0b);
  cvt_hw<<<(HID * KDIM) / 256, 256, 0, stream>>>(hw_w1, w1b);
  cvt_kernel<<<(PDIM * KDIM) / 256, 256, 0, stream>>>(proj_w, pwb, PDIM * KDIM);
  conv_wprep<<<(262144 + 2048 + 4192 + 255) / 256, 256, 0, stream>>>(
      cw[0], cw[1], cw[2], cw[3], cw[4], cw[5], cw[6],
      cb[0], cb[1], cb[2], cb[3], cb[4], cb[5], cb[6], emb,
      convWb, convBc, embb);

  // Conv: one launch per width class; small classes use 16-token blocks
  // so their grids reach 256+ blocks (were 128 = half the CUs idle).
  conv_k<1, 4, 72, 4><<<dim3(256, 1), 256, 0, stream>>>(chars, embb, convWb,
                                                        convBc, h, 0);
  conv_k<2, 3, 56, 4><<<dim3(256, 3), 256, 0, stream>>>(chars, embb, convWb,
                                                        convBc, h, 64);
  conv_k<3, 3, 56, 8><<<dim3(128, 12), 256, 0, stream>>>(chars, embb, convWb,
                                                         convBc, h, 256);
  conv_k<4, 3, 56, 8><<<dim3(128, 16), 256, 0, stream>>>(chars, embb, convWb,
                                                         convBc, h, 1024);

  gemm_hw<<<dim3(HID / 128, NTOK / 128), 256, 0, stream>>>(h, w0b, hw_b0, h2);
  gemm_hw<<<dim3(HID / 128, NTOK / 128), 256, 0, stream>>>(h2, w1b, hw_b1, h);
  gemm_proj<<<dim3(PDIM / 128, NTOK / 32), 256, 0, stream>>>(h, pwb, out,
                                                             proj_b);
}

// Round 9
// 543.791 us; speedup vs baseline: 1.1290x; 1.1290x over previous
//
#include <hip/hip_runtime.h>
#include <hip/hip_bf16.h>

// ---------------------------------------------------------------------------
// ConvTokenEmbedder: char-CNN -> 2x highway -> projection
// R9: re-anchor on best-known config (R5 GEMM structure, R7 conv structure).
//     Evidence: MFMA-busy is constant 28us across R5/R7/R8; R7 (XOR swizzle)
//     and R8 (fragment-order) both regressed the wrapper (129->151->164).
//     New (orthogonal, outside the K-loop): L2 block-swizzle on gemm_hw;
//     all weight-prep merged into ONE kernel (fewer dispatch gaps).
// ---------------------------------------------------------------------------

#define NTOK 4096
#define NF   2048
#define KDIM 2048
#define HID  4096
#define PDIM 512

typedef __attribute__((ext_vector_type(4))) float floatx4;
typedef __attribute__((ext_vector_type(8))) short shortx8;

__device__ inline void async_copy16(const void* g, void* l) {
  __builtin_amdgcn_global_load_lds(
      (const __attribute__((address_space(1))) void*)(uintptr_t)g,
      (__attribute__((address_space(3))) void*)(uint32_t)(uintptr_t)l,
      16, 0, 0);
}

// ---------------------------------------------------------------------------
// Single prep kernel: hw weights (nl/gate interleaved bf16), proj weights,
// conv weights (Wb[ch][kp], kp=k*16+d, K padded to 128), bias pack, bf16 emb.
// Flat-index ranges over 18,094,176 elements.
// ---------------------------------------------------------------------------
#define PR_W0  0
#define PR_W1  8388608
#define PR_PW  16777216
#define PR_CW  17825792
#define PR_CB  18087936
#define PR_EM  18089984
#define PR_END 18094176

__global__ __launch_bounds__(256) void prep_all(
    const float* __restrict__ hw_w0, const float* __restrict__ hw_w1,
    const float* __restrict__ proj_w,
    const float* __restrict__ w0, const float* __restrict__ w1,
    const float* __restrict__ w2, const float* __restrict__ w3,
    const float* __restrict__ w4, const float* __restrict__ w5,
    const float* __restrict__ w6,
    const float* __restrict__ b0, const float* __restrict__ b1,
    const float* __restrict__ b2, const float* __restrict__ b3,
    const float* __restrict__ b4, const float* __restrict__ b5,
    const float* __restrict__ b6, const float* __restrict__ emb,
    __hip_bfloat16* __restrict__ w0b, __hip_bfloat16* __restrict__ w1b,
    __hip_bfloat16* __restrict__ pwb, __hip_bfloat16* __restrict__ Wb,
    float* __restrict__ Bc, __hip_bfloat16* __restrict__ embb) {
  int idx = blockIdx.x * 256 + threadIdx.x;
  if (idx >= PR_END) return;
  const int start[7] = {0, 32, 64, 128, 256, 512, 1024};
  const float* ws[7] = {w0, w1, w2, w3, w4, w5, w6};
  const float* bs[7] = {b0, b1, b2, b3, b4, b5, b6};
  if (idx < PR_PW) {
    // highway weights, nl/gate row interleave
    const float* s = (idx < PR_W1) ? hw_w0 : hw_w1;
    __hip_bfloat16* d = (idx < PR_W1) ? w0b : w1b;
    int i = (idx < PR_W1) ? idx : idx - PR_W1;
    int r = i >> 11, k = i & 2047;
    int sr = (r >> 1) + (r & 1) * 2048;
    d[i] = __float2bfloat16(s[(size_t)sr * 2048 + k]);
  } else if (idx < PR_CW) {
    int i = idx - PR_PW;
    pwb[i] = __float2bfloat16(proj_w[i]);
  } else if (idx < PR_CB) {
    int i = idx - PR_CW;
    int ch = i >> 7, kp = i & 127;
    int f = (ch >= 32) + (ch >= 64) + (ch >= 128) + (ch >= 256) +
            (ch >= 512) + (ch >= 1024);
    int w = f + 1, lc = ch - start[f];
    int d = kp & 15, k = kp >> 4;
    float v = (k < w) ? ws[f][((size_t)lc * 16 + d) * w + k] : 0.f;
    Wb[i] = __float2bfloat16(v);
  } else if (idx < PR_EM) {
    int ch = idx - PR_CB;
    int f = (ch >= 32) + (ch >= 64) + (ch >= 128) + (ch >= 256) +
            (ch >= 512) + (ch >= 1024);
    Bc[ch] = bs[f][ch - start[f]];
  } else {
    int e = idx - PR_EM;
    embb[e] = __float2bfloat16(emb[e]);
  }
}

// ---------------------------------------------------------------------------
// Conv kernel (R7 structure). Block: 64 channels x 32 tokens; 8 groups of
// 4 tokens (one per wave). A = X window tile (rows=t, stride 24 -> 2-way),
// B = W register-resident. Epilogue: register max over t, shfl 16/32,
// cndmask select, one coalesced 128B store per wave per group.
// ---------------------------------------------------------------------------
template <int NKT, int NT, int ROWS>
__global__ __launch_bounds__(256) void conv_k(
    const int* __restrict__ chars, const __hip_bfloat16* __restrict__ embb,
    const __hip_bfloat16* __restrict__ Wb, const float* __restrict__ bias,
    __hip_bfloat16* __restrict__ h, int chbase) {
  __shared__ __align__(16) __hip_bfloat16 Xs[2 * 4 * ROWS * 24];
  int tid = threadIdx.x, wave = tid >> 6, lane = tid & 63;
  int frow = lane & 15, q = lane >> 4;
  int chb = chbase + blockIdx.y * 64;
  int tokbase = blockIdx.x * 32;

  shortx8 wreg[NKT][4];
#pragma unroll
  for (int kt = 0; kt < NKT; ++kt)
#pragma unroll
    for (int j = 0; j < 4; ++j)
      wreg[kt][j] = *(const shortx8*)(
          Wb + (size_t)(chb + j * 16 + frow) * 128 + kt * 32 + q * 8);

  float blane = bias[chb + lane];
  int Tvj[4];
#pragma unroll
  for (int j = 0; j < 4; ++j) {
    int ch = chb + j * 16 + frow;
    int w = 1 + (ch >= 32) + (ch >= 64) + (ch >= 128) + (ch >= 256) +
            (ch >= 512) + (ch >= 1024);
    Tvj[j] = 51 - w;
  }

  auto stage = [&](int g, int buf) {
    constexpr int NST = 4 * ROWS;
#pragma unroll
    for (int rep = 0; rep < (NST + 255) / 256; ++rep) {
      int rr = tid + rep * 256;
      if (rr < NST) {
        int tk = rr / ROWS, r = rr - tk * ROWS;
        __hip_bfloat16* dst = Xs + ((size_t)(buf * 4 + tk) * ROWS + r) * 24;
        if (r < 50) {
          int c = chars[(size_t)(tokbase + g * 4 + tk) * 50 + r];
          const shortx8* e = (const shortx8*)(embb + c * 16);
          *(shortx8*)(dst) = e[0];
          *(shortx8*)(dst + 8) = e[1];
        } else if (g <= 1) {
          shortx8 z = {0, 0, 0, 0, 0, 0, 0, 0};
          *(shortx8*)(dst) = z;
          *(shortx8*)(dst + 8) = z;
        }
      }
    }
  };

  stage(0, 0);
  __syncthreads();

  const floatx4 zero = {0.f, 0.f, 0.f, 0.f};
#pragma unroll 1
  for (int g = 0; g < 8; ++g) {
    if (g < 7) stage(g + 1, (g + 1) & 1);

    const __hip_bfloat16* Xw = Xs + (size_t)((g & 1) * 4 + wave) * ROWS * 24;
    floatx4 acc[NT][4];

#pragma unroll
    for (int kt = 0; kt < NKT; ++kt) {
      int kk = kt * 2 + (q >> 1);
      int d0 = (q & 1) * 8;
      shortx8 xf[NT];
#pragma unroll
      for (int i = 0; i < NT; ++i)
        xf[i] = *(const shortx8*)(Xw + (i * 16 + frow + kk) * 24 + d0);
#pragma unroll
      for (int i = 0; i < NT; ++i)
#pragma unroll
        for (int j = 0; j < 4; ++j) {
          if (kt == 0)
            acc[i][j] = __builtin_amdgcn_mfma_f32_16x16x32_bf16(
                xf[i], wreg[0][j], zero, 0, 0, 0);
          else
            acc[i][j] = __builtin_amdgcn_mfma_f32_16x16x32_bf16(
                xf[i], wreg[kt][j], acc[i][j], 0, 0, 0);
        }
    }

    float vj[4];
#pragma unroll
    for (int j = 0; j < 4; ++j) {
      float v = -1e30f;
#pragma unroll
      for (int i = 0; i < NT; ++i) {
#pragma unroll
        for (int r = 0; r < 4; ++r) {
          if (i < 2) {
            v = fmaxf(v, acc[i][j][r]);
          } else {
            int t = i * 16 + q * 4 + r;
            if (t < Tvj[j]) v = fmaxf(v, acc[i][j][r]);
          }
        }
      }
      v = fmaxf(v, __shfl_xor(v, 16));
      v = fmaxf(v, __shfl_xor(v, 32));
      vj[j] = v;
    }
    float r0 = (q & 2) ? vj[2] : vj[0];
    float r1 = (q & 2) ? vj[3] : vj[1];
    float rv = (q & 1) ? r1 : r0;
    int tok = tokbase + g * 4 + wave;
    h[(size_t)tok * NF + chb + lane] =
        __float2bfloat16(fmaxf(rv + blane, 0.f));
    __syncthreads();
  }
}

// ---------------------------------------------------------------------------
// Highway-fused GEMM (R5 structure: BK=32, natural LDS layout). 128x128 tile.
// L2 swizzle: id -> bn=(id>>7)*4+(id&3), bm=(id>>2)&31 (bijective) so
// concurrent blocks share a 4-tile A band; B L3-resident after band 0.
// Epilogue: pairs even/odd cols via shfl_xor(1), g=sigmoid(gate+b),
// h' = g*h + (1-g)*relu(nl+b), writes Hdst.
// ---------------------------------------------------------------------------
__global__ __launch_bounds__(256) void gemm_hw(
    const __hip_bfloat16* __restrict__ A, const __hip_bfloat16* __restrict__ B,
    const float* __restrict__ hwb, __hip_bfloat16* __restrict__ Hdst) {
  const int K = KDIM;
  __shared__ __align__(16) __hip_bfloat16 As[128 * 32];
  __shared__ __align__(16) __hip_bfloat16 Bs[128 * 32];
  int tid = threadIdx.x;
  int wave = tid >> 6, lane = tid & 63;
  int wr = wave >> 1, wc = wave & 1;
  int id = blockIdx.y * 32 + blockIdx.x;
  int bn = (id >> 7) * 4 + (id & 3);
  int bm = (id >> 2) & 31;

  int srow = lane >> 2;
  int skq  = (lane & 3) * 8;
  int frow = lane & 15;
  int fkq  = (lane >> 4) * 8;
  int q    = lane >> 4;

  floatx4 acc[4][4];
  floatx4 zero = {0.f, 0.f, 0.f, 0.f};
#pragma unroll
  for (int i = 0; i < 4; ++i)
#pragma unroll
    for (int j = 0; j < 4; ++j) acc[i][j] = zero;

  const __hip_bfloat16* Ab = A + (size_t)bn * 128 * K;
  const __hip_bfloat16* Bb = B + (size_t)bm * 128 * K;

  for (int kb = 0; kb < K; kb += 32) {
    __syncthreads();
#pragma unroll
    for (int it = 0; it < 2; ++it) {
      int seg = wave * 2 + it;
      async_copy16(Ab + (size_t)(seg * 16 + srow) * K + kb + skq,
                   (char*)As + seg * 1024);
      async_copy16(Bb + (size_t)(seg * 16 + srow) * K + kb + skq,
                   (char*)Bs + seg * 1024);
    }
    __syncthreads();

    shortx8 af[4], bf[4];
#pragma unroll
    for (int i = 0; i < 4; ++i)
      af[i] = *(const shortx8*)(As + (wr * 64 + i * 16 + frow) * 32 + fkq);
#pragma unroll
    for (int j = 0; j < 4; ++j)
      bf[j] = *(const shortx8*)(Bs + (wc * 64 + j * 16 + frow) * 32 + fkq);
#pragma unroll
    for (int i = 0; i < 4; ++i)
#pragma unroll
      for (int j = 0; j < 4; ++j)
        acc[i][j] =
            __builtin_amdgcn_mfma_f32_16x16x32_bf16(af[i], bf[j], acc[i][j], 0, 0, 0);
  }

  int crow0 = bn * 128 + wr * 64 + q * 4;
  int ccol0 = bm * 128 + wc * 64 + frow;
#pragma unroll
  for (int i = 0; i < 4; ++i)
#pragma unroll
    for (int j = 0; j < 4; ++j) {
      int gcol = ccol0 + j * 16;
      float bb = (gcol & 1) ? hwb[2048 + (gcol >> 1)] : hwb[gcol >> 1];
#pragma unroll
      for (int r = 0; r < 4; ++r) {
        int row = crow0 + i * 16 + r;
        float v = acc[i][j][r] + bb;
        float partner = __shfl_xor(v, 1);
        if (!(lane & 1)) {  // even lane holds nl, partner is gate pre-act
          float gte = 1.f / (1.f + expf(-partner));
          int ch = gcol >> 1;
          float hold = __bfloat162float(A[(size_t)row * 2048 + ch]);
          float hnew = gte * hold + (1.f - gte) * fmaxf(v, 0.f);
          Hdst[(size_t)row * 2048 + ch] = __float2bfloat16(hnew);
        }
      }
    }
}

// ---------------------------------------------------------------------------
// Projection GEMM: 32x128 tile (grid 4x128 = 512 blocks), BK=32, natural
// LDS layout (R5-style staging). C fp32 + bias.
// ---------------------------------------------------------------------------
__global__ __launch_bounds__(256) void gemm_proj(
    const __hip_bfloat16* __restrict__ A, const __hip_bfloat16* __restrict__ B,
    float* __restrict__ C, const float* __restrict__ bias) {
  const int K = KDIM;
  __shared__ __align__(16) __hip_bfloat16 As[32 * 32];
  __shared__ __align__(16) __hip_bfloat16 Bs[128 * 32];
  int tid = threadIdx.x;
  int wave = tid >> 6, lane = tid & 63;
  int wr = wave >> 1, wc = wave & 1;
  int bn = blockIdx.y, bm = blockIdx.x;

  int srow = lane >> 2;
  int skq  = (lane & 3) * 8;
  int frow = lane & 15;
  int fkq  = (lane >> 4) * 8;
  int q    = lane >> 4;

  floatx4 acc[4];
  floatx4 zero = {0.f, 0.f, 0.f, 0.f};
#pragma unroll
  for (int j = 0; j < 4; ++j) acc[j] = zero;

  const __hip_bfloat16* Ab = A + (size_t)bn * 32 * K;
  const __hip_bfloat16* Bb = B + (size_t)bm * 128 * K;

  for (int kb = 0; kb < K; kb += 32) {
    __syncthreads();
    if (wave < 2)  // As: 2 segs x 16 rows
      async_copy16(Ab + (size_t)(wave * 16 + srow) * K + kb + skq,
                   (char*)As + wave * 1024);
#pragma unroll
    for (int it = 0; it < 2; ++it) {
      int seg = wave * 2 + it;  // Bs: 8 segs x 16 rows
      async_copy16(Bb + (size_t)(seg * 16 + srow) * K + kb + skq,
                   (char*)Bs + seg * 1024);
    }
    __syncthreads();

    shortx8 af, bf[4];
    af = *(const shortx8*)(As + (wr * 16 + frow) * 32 + fkq);
#pragma unroll
    for (int j = 0; j < 4; ++j)
      bf[j] = *(const shortx8*)(Bs + (wc * 64 + j * 16 + frow) * 32 + fkq);
#pragma unroll
    for (int j = 0; j < 4; ++j)
      acc[j] = __builtin_amdgcn_mfma_f32_16x16x32_bf16(af, bf[j], acc[j],
                                                        0, 0, 0);
  }

  int crow0 = bn * 32 + wr * 16 + q * 4;
  int ccol0 = bm * 128 + wc * 64 + frow;
#pragma unroll
  for (int j = 0; j < 4; ++j) {
    int c = ccol0 + j * 16;
#pragma unroll
    for (int r = 0; r < 4; ++r) {
      int row = crow0 + r;
      C[(size_t)row * PDIM + c] = acc[j][r] + bias[c];
    }
  }
}

// ---------------------------------------------------------------------------
extern "C" void kernel_launch(void* const* d_in, const int* in_sizes, int n_in,
                              void* d_out, int out_size, void* d_ws, size_t ws_size,
                              hipStream_t stream) {
  const int*   chars  = (const int*)d_in[1];
  const float* emb    = (const float*)d_in[2];
  const float* cw[7];
  const float* cb[7];
  for (int i = 0; i < 7; ++i) {
    cw[i] = (const float*)d_in[3 + 2 * i];
    cb[i] = (const float*)d_in[4 + 2 * i];
  }
  const float* hw_w0  = (const float*)d_in[17];
  const float* hw_b0  = (const float*)d_in[18];
  const float* hw_w1  = (const float*)d_in[19];
  const float* hw_b1  = (const float*)d_in[20];
  const float* proj_w = (const float*)d_in[21];
  const float* proj_b = (const float*)d_in[22];
  float* out = (float*)d_out;

  // Workspace (82 MiB):
  //   [0,16)   h   bf16 4096x2048      [16,32) h2  bf16 4096x2048
  //   [32,48)  convWb 512KB + convBc 8KB + embb 8.4KB
  //   [48,64)  w0b  [64,80) w1b  [80,82) pwb
  char* ws = (char*)d_ws;
  __hip_bfloat16* h      = (__hip_bfloat16*)(ws);
  __hip_bfloat16* h2     = (__hip_bfloat16*)(ws + (16ull << 20));
  __hip_bfloat16* convWb = (__hip_bfloat16*)(ws + (32ull << 20));
  float*          convBc = (float*)(ws + (32ull << 20) + 524288);
  __hip_bfloat16* embb   = (__hip_bfloat16*)(ws + (32ull << 20) + 524288 + 8192);
  __hip_bfloat16* w0b    = (__hip_bfloat16*)(ws + (48ull << 20));
  __hip_bfloat16* w1b    = (__hip_bfloat16*)(ws + (64ull << 20));
  __hip_bfloat16* pwb    = (__hip_bfloat16*)(ws + (80ull << 20));

  prep_all<<<(PR_END + 255) / 256, 256, 0, stream>>>(
      hw_w0, hw_w1, proj_w,
      cw[0], cw[1], cw[2], cw[3], cw[4], cw[5], cw[6],
      cb[0], cb[1], cb[2], cb[3], cb[4], cb[5], cb[6], emb,
      w0b, w1b, pwb, convWb, convBc, embb);

  // Conv: one launch per width class (R7 grids).
  conv_k<1, 4, 72><<<dim3(128, 1), 256, 0, stream>>>(chars, embb, convWb,
                                                     convBc, h, 0);
  conv_k<2, 3, 56><<<dim3(128, 3), 256, 0, stream>>>(chars, embb, convWb,
                                                     convBc, h, 64);
  conv_k<3, 3, 56><<<dim3(128, 12), 256, 0, stream>>>(chars, embb, convWb,
                                                      convBc, h, 256);
  conv_k<4, 3, 56><<<dim3(128, 16), 256, 0, stream>>>(chars, embb, convWb,
                                                      convBc, h, 1024);

  gemm_hw<<<dim3(32, 32), 256, 0, stream>>>(h, w0b, hw_b0, h2);
  gemm_hw<<<dim3(32, 32), 256, 0, stream>>>(h2, w1b, hw_b1, h);
  gemm_proj<<<dim3(PDIM / 128, NTOK / 32), 256, 0, stream>>>(h, pwb, out,
                                                             proj_b);
}